// Round 8
// baseline (23956.941 us; speedup 1.0000x reference)
//
#include <hip/hip_runtime.h>
#include <hip/hip_bf16.h>

#define T_STEPS 2048
#define HID 256
#define INF 72
#define OUTF 90
#define HSTR 528          // LDS h row stride for gi_mfma (bytes)

typedef __attribute__((ext_vector_type(4))) float f32x4;
typedef __attribute__((ext_vector_type(8))) short s16x8;
typedef unsigned long long u64;

__device__ __forceinline__ unsigned short f2bf(float f) {
  union { float f; unsigned u; } v; v.f = f;
  unsigned r = (v.u + 0x7FFFu + ((v.u >> 16) & 1u)) >> 16;   // RNE
  return (unsigned short)r;
}
__device__ __forceinline__ float bf2f(unsigned short s) {
  union { unsigned u; float f; } v; v.u = ((unsigned)s) << 16;
  return v.f;
}
__device__ __forceinline__ float sigm(float x) {
  return __builtin_amdgcn_rcpf(1.f + __builtin_amdgcn_exp2f(-1.44269504f * x));
}
__device__ __forceinline__ float tanh_f(float x) {
  return 1.f - 2.f * __builtin_amdgcn_rcpf(1.f + __builtin_amdgcn_exp2f(2.88539008f * x));
}

// ---- relaxed agent-scope primitives (single sc1 ops: NO buffer_inv / writeback) ----
__device__ __forceinline__ u64 ld64(const u64* p) {
  return __hip_atomic_load(p, __ATOMIC_RELAXED, __HIP_MEMORY_SCOPE_AGENT);
}
__device__ __forceinline__ void st64(u64* p, u64 v) {
  __hip_atomic_store(p, v, __ATOMIC_RELAXED, __HIP_MEMORY_SCOPE_AGENT);
}
__device__ __forceinline__ void stflag(unsigned* p, unsigned v) {
  __hip_atomic_store(p, v, __ATOMIC_RELAXED, __HIP_MEMORY_SCOPE_AGENT);
}
// wait until min of 16 packed u32 flags >= target
__device__ __forceinline__ void wait16(const unsigned* flags, unsigned target) {
  const u64* fl = (const u64*)flags;
  unsigned mn;
  do {
    mn = 0xFFFFFFFFu;
#pragma unroll
    for (int i = 0; i < 8; ++i) {
      u64 v = ld64(fl + i);
      unsigned a = (unsigned)v, b = (unsigned)(v >> 32);
      mn = a < mn ? a : mn;
      mn = b < mn ? b : mn;
    }
    if (mn < target) __builtin_amdgcn_s_sleep(1);
  } while (mn < target);
}
// load one 16-short gi record (32B) as 4 relaxed u64s
__device__ __forceinline__ void ld_gi(const unsigned short* p, s16x8& a, s16x8& b) {
  const u64* q = (const u64*)p;
  union { u64 u[2]; s16x8 v; } x, y;
  x.u[0] = ld64(q + 0); x.u[1] = ld64(q + 1);
  y.u[0] = ld64(q + 2); y.u[1] = ld64(q + 3);
  a = x.v; b = y.v;
}

// ---------------- input projection: h0 = relu(x @ W1^T + b1) ----------------
__global__ __launch_bounds__(256) void inproj(const float* __restrict__ x,
                                              const float* __restrict__ W1,
                                              const float* __restrict__ b1,
                                              float* __restrict__ h0) {
  __shared__ float w1s[HID][INF + 1];
  __shared__ float xs[16][INF];
  const int tid = threadIdx.x;
  const int r0 = blockIdx.x * 16;
  for (int i = tid; i < HID * INF; i += 256) w1s[i / INF][i % INF] = W1[i];
  for (int i = tid; i < 16 * INF; i += 256)
    xs[i / INF][i % INF] = x[(size_t)(r0 + i / INF) * INF + (i % INF)];
  __syncthreads();
  const float bj = b1[tid];
  for (int r = 0; r < 16; ++r) {
    float acc = bj;
#pragma unroll 8
    for (int k = 0; k < INF; ++k) acc += xs[r][k] * w1s[tid][k];
    h0[(size_t)(r0 + r) * HID + tid] = fmaxf(acc, 0.f);
  }
}

// ---------------- pack f32 -> bf16 ----------------
__global__ __launch_bounds__(256) void wpack(const float* __restrict__ w,
                                             unsigned short* __restrict__ o) {
  const size_t i = ((size_t)blockIdx.x * 256 + threadIdx.x) * 8;
  f32x4 a = *(const f32x4*)(w + i);
  f32x4 b = *(const f32x4*)(w + i + 4);
  s16x8 v;
#pragma unroll
  for (int e = 0; e < 4; ++e) { v[e] = (short)f2bf(a[e]); v[4 + e] = (short)f2bf(b[e]); }
  *(s16x8*)(o + i) = v;
}

// ------------- layer-1 gi GEMM (MFMA, swapped orientation): one block per t -------------
// g^T = Wih1 . h0^T : lane (j,hi) of tile sw holds g[q][unit=sw*16+hi*4+r][b=j]
__global__ __launch_bounds__(256) void gi_mfma(const float* __restrict__ h,
                                               const unsigned short* __restrict__ wb,
                                               const float* __restrict__ bih,
                                               const float* __restrict__ bhh,
                                               unsigned short* __restrict__ gi) {
  __shared__ __align__(16) char hs[16 * HSTR];
  __shared__ float bs[1024];
  const int tid = threadIdx.x;
  const int t = blockIdx.x;
  const int lane = tid & 63;
  const int wg = tid >> 6;
  const int j = lane & 15;
  const int hi = lane >> 4;
  for (int i = tid; i < 1024; i += 256) bs[i] = bih[i] + bhh[i];
  {
    const int row = tid >> 4;
    const int c0 = (tid & 15) * 16;
    const float* src = h + ((size_t)t * 16 + row) * 256 + c0;
    f32x4 v0 = *(const f32x4*)(src);
    f32x4 v1 = *(const f32x4*)(src + 4);
    f32x4 v2 = *(const f32x4*)(src + 8);
    f32x4 v3 = *(const f32x4*)(src + 12);
    s16x8 p0, p1;
#pragma unroll
    for (int e = 0; e < 4; ++e) {
      p0[e] = (short)f2bf(v0[e]); p0[4 + e] = (short)f2bf(v1[e]);
      p1[e] = (short)f2bf(v2[e]); p1[4 + e] = (short)f2bf(v3[e]);
    }
    *(s16x8*)(hs + row * HSTR + c0 * 2) = p0;
    *(s16x8*)(hs + row * HSTR + c0 * 2 + 16) = p1;
  }
  __syncthreads();
  const int hread = j * HSTR + hi * 16;
  f32x4 acc[4][4] = {};   // [ug2][q]
#pragma unroll
  for (int kt = 0; kt < 8; ++kt) {
    const int k = kt * 32 + hi * 8;
    const s16x8 a = *(const s16x8*)(hs + hread + kt * 64);   // h[b=j][k] (B-frag)
#pragma unroll
    for (int ug2 = 0; ug2 < 4; ++ug2)
#pragma unroll
      for (int q = 0; q < 4; ++q) {
        const s16x8 bw = *(const s16x8*)(wb + (((size_t)(q << 8) + wg * 64 + ug2 * 16 + j) << 8) + k);
        acc[ug2][q] = __builtin_amdgcn_mfma_f32_16x16x32_bf16(bw, a, acc[ug2][q], 0, 0, 0);
      }
  }
#pragma unroll
  for (int ug2 = 0; ug2 < 4; ++ug2) {
    const int sw = wg * 4 + ug2;
    const int uT = sw * 16 + hi * 4;
    s16x8 o0, o1;
#pragma unroll
    for (int r = 0; r < 4; ++r) {
      o0[r]     = (short)f2bf(acc[ug2][0][r] + bs[uT + r]);
      o0[4 + r] = (short)f2bf(acc[ug2][1][r] + bs[256 + uT + r]);
      o1[r]     = (short)f2bf(acc[ug2][2][r] + bs[512 + uT + r]);
      o1[4 + r] = (short)f2bf(acc[ug2][3][r] + bs[768 + uT + r]);
    }
    unsigned short* dst = gi + ((size_t)(t * 16 + sw) * 64 + lane) * 16;
    *(s16x8*)(dst) = o0;
    *(s16x8*)(dst + 8) = o1;
  }
}

// ============ fused pipeline: scan1{0,8} | gi2{2,10} | scan2{1,9} ============
// Swapped orientation: lane (j,hi) of wave w owns units uB+hi*4..+3 for batch j.
// No LDS, no s_barrier in the scan step: per-wave flags, relaxed sc1 exchange.

template <int ROLE>   // 0: layer1 (ys->hb1 via u64 atomics); 1: layer2 (ys->hout f32)
__device__ __forceinline__ void scan2cu(
    const unsigned short* __restrict__ gi,    // [T][16][64][16] fragment file
    const unsigned short* __restrict__ whbL,  // Whh bf16 [1024][256]
    const int* __restrict__ lengths,
    unsigned short* __restrict__ hb1,
    float* __restrict__ hout,
    unsigned short* hx,                       // [4][16][256] bf16 exchange
    unsigned* flags,                          // 16 per-wave flags (this layer pair)
    unsigned* creds,                          // ROLE1: 2 gi2 credits (one u64)
    int half)
{
  const int tid  = threadIdx.x;
  const int lane = tid & 63;
  const int w    = tid >> 6;     // 0..7
  const int j    = lane & 15;    // batch
  const int hi   = lane >> 4;
  const int uB   = half * 128 + w * 16;
  const int myf  = half * 8 + w;

  s16x8 wfr[32];   // A-frag: lane holds W[unit=uB+j][k=kt*32+hi*8..] for 4 gates x 8 kt
#pragma unroll
  for (int kt = 0; kt < 8; ++kt)
#pragma unroll
    for (int q = 0; q < 4; ++q)
      wfr[kt * 4 + q] =
          *(const s16x8*)(whbL + ((size_t)(q * 256 + uB + j) << 8) + kt * 32 + hi * 8);

  const int len = lengths[j];
  float c[4] = {};
  unsigned short hprev[4] = {};

  const unsigned short* gp = gi + ((size_t)(half * 8 + w) * 64 + lane) * 16;

  unsigned cred = 0;
  if (ROLE == 1) {   // initial credit BEFORE first gi touch
    const u64* cp = (const u64*)creds;
    while (cred < 8u) {
      u64 v = ld64(cp);
      unsigned a = (unsigned)v, b = (unsigned)(v >> 32);
      cred = a < b ? a : b;
      if (cred < 8u) __builtin_amdgcn_s_sleep(2);
    }
  }
  s16x8 gE0, gE1, gO0, gO1;
  ld_gi(gp, gE0, gE1);
  ld_gi(gp + 16384, gO0, gO1);

  for (int tg = 0; tg < T_STEPS; tg += 4) {
    if (ROLE == 1) {
      const unsigned target = (tg + 8 <= T_STEPS) ? (unsigned)(tg + 8) : (unsigned)T_STEPS;
      const u64* cp = (const u64*)creds;
      while (cred < target) {
        u64 v = ld64(cp);
        unsigned a = (unsigned)v, b = (unsigned)(v >> 32);
        cred = a < b ? a : b;
        if (cred < target) __builtin_amdgcn_s_sleep(2);
      }
    }
#pragma unroll
    for (int ts = 0; ts < 4; ++ts) {
      const int t = tg + ts;
      s16x8& g0 = (ts & 1) ? gO0 : gE0;
      s16x8& g1 = (ts & 1) ? gO1 : gE1;

      wait16(flags, (unsigned)t);          // all 16 waves published h(t)

      // h B-frags: lane needs h[b=j][k=kt*32+hi*8..+7] = 16B = 2 u64s per kt
      const u64* hsrc = (const u64*)(hx + (size_t)(t & 3) * 4096 + j * 256) + hi * 2;
      s16x8 av[8];
#pragma unroll
      for (int kt = 0; kt < 8; ++kt) {
        union { u64 u[2]; s16x8 v; } x;
        x.u[0] = ld64(hsrc + kt * 8);
        x.u[1] = ld64(hsrc + kt * 8 + 1);
        av[kt] = x.v;
      }

      f32x4 acc[4];
#pragma unroll
      for (int r = 0; r < 4; ++r) {
        acc[0][r] = bf2f((unsigned short)g0[r]);
        acc[1][r] = bf2f((unsigned short)g0[4 + r]);
        acc[2][r] = bf2f((unsigned short)g1[r]);
        acc[3][r] = bf2f((unsigned short)g1[4 + r]);
      }
      {  // 2-step-deep gi prefetch into the just-freed register set
        const int tn = (t + 2 < T_STEPS) ? t + 2 : T_STEPS - 1;
        ld_gi(gp + (size_t)tn * 16384, g0, g1);
      }
#pragma unroll
      for (int kt = 0; kt < 8; ++kt)
#pragma unroll
        for (int q = 0; q < 4; ++q)
          acc[q] = __builtin_amdgcn_mfma_f32_16x16x32_bf16(wfr[kt * 4 + q], av[kt], acc[q], 0, 0, 0);

      u64 hpk = 0, ypk = 0;
      f32x4 yv;
      const bool m = t < len;
#pragma unroll
      for (int r = 0; r < 4; ++r) {
        const float i_  = sigm(acc[0][r]);
        const float f_  = sigm(acc[1][r]);
        const float tg_ = tanh_f(acc[2][r]);
        const float o_  = sigm(acc[3][r]);
        const float cn = f_ * c[r] + i_ * tg_;
        const float hv = o_ * tanh_f(cn);
        c[r] = m ? cn : c[r];
        const unsigned short hb = m ? f2bf(hv) : hprev[r];
        hprev[r] = hb;
        hpk |= (u64)hb << (16 * r);
        if (ROLE == 0) ypk |= (u64)(m ? hb : (unsigned short)0) << (16 * r);
        else           yv[r] = m ? hv : 0.f;
      }
      // publish h(t+1): one u64 sc1 store, then ys, then drain, then flag
      st64((u64*)hx + ((((t + 1) & 3) * 4096 + j * 256 + uB + hi * 4) >> 2), hpk);
      if (ROLE == 0)
        st64((u64*)hb1 + (((size_t)t * 4096 + j * 256 + uB + hi * 4) >> 2), ypk);
      else
        *(f32x4*)(hout + ((size_t)t * 16 + j) * 256 + uB + hi * 4) = yv;
      asm volatile("s_waitcnt vmcnt(0)" ::: "memory");
      if (lane == 0) stflag(flags + myf, (unsigned)(t + 1));
    }
  }
}

// ---- gi2 producer CU: 8 waves, one 16-unit tile each, Wih2 slice in 128 VGPRs ----
__device__ __forceinline__ void gi2b(int cu,
    const unsigned short* __restrict__ hb1,
    const unsigned short* __restrict__ wb2,
    const float* __restrict__ bih2, const float* __restrict__ bhh2,
    unsigned short* __restrict__ gf2,
    unsigned* flags1, unsigned* cred)
{
  const int tid = threadIdx.x;
  const int lane = tid & 63;
  const int w = tid >> 6;
  const int j = lane & 15;
  const int hi = lane >> 4;
  const int sw = cu * 8 + w;

  s16x8 wfr[32];
  float bsum[4][4];
#pragma unroll
  for (int kt = 0; kt < 8; ++kt)
#pragma unroll
    for (int q = 0; q < 4; ++q)
      wfr[kt * 4 + q] =
          *(const s16x8*)(wb2 + ((size_t)(q * 256 + sw * 16 + j) << 8) + kt * 32 + hi * 8);
#pragma unroll
  for (int q = 0; q < 4; ++q)
#pragma unroll
    for (int r = 0; r < 4; ++r) {
      const int col = q * 256 + sw * 16 + hi * 4 + r;
      bsum[q][r] = bih2[col] + bhh2[col];
    }

  for (int tg = 0; tg < T_STEPS; tg += 4) {
    wait16(flags1, (unsigned)(tg + 4));    // hb1[tg..tg+3] fully published
#pragma unroll
    for (int ts = 0; ts < 4; ++ts) {
      const int t = tg + ts;
      const u64* ab = (const u64*)(hb1 + (size_t)t * 4096 + j * 256) + hi * 2;
      s16x8 av[8];
#pragma unroll
      for (int kt = 0; kt < 8; ++kt) {
        union { u64 u[2]; s16x8 v; } x;
        x.u[0] = ld64(ab + kt * 8);
        x.u[1] = ld64(ab + kt * 8 + 1);
        av[kt] = x.v;
      }
      f32x4 acc[4];
#pragma unroll
      for (int q = 0; q < 4; ++q)
#pragma unroll
        for (int r = 0; r < 4; ++r) acc[q][r] = bsum[q][r];
#pragma unroll
      for (int kt = 0; kt < 8; ++kt)
#pragma unroll
        for (int q = 0; q < 4; ++q)
          acc[q] = __builtin_amdgcn_mfma_f32_16x16x32_bf16(wfr[kt * 4 + q], av[kt], acc[q], 0, 0, 0);
      u64 p0 = 0, p1 = 0;
#pragma unroll
      for (int r = 0; r < 4; ++r) {
        p0 |= (u64)f2bf(acc[0][r]) << (16 * r);
        p1 |= (u64)f2bf(acc[2][r]) << (16 * r);
      }
      u64 q0 = 0, q1 = 0;
#pragma unroll
      for (int r = 0; r < 4; ++r) {
        q0 |= (u64)f2bf(acc[1][r]) << (16 * r);
        q1 |= (u64)f2bf(acc[3][r]) << (16 * r);
      }
      u64* dst = (u64*)gf2 + ((size_t)(t * 16 + sw) * 64 + lane) * 4;
      st64(dst, p0); st64(dst + 1, q0); st64(dst + 2, p1); st64(dst + 3, q1);
    }
    asm volatile("s_waitcnt vmcnt(0)" ::: "memory");
    __builtin_amdgcn_s_barrier();
    if (tid == 0) stflag(cred, (unsigned)(tg + 4));
  }
}

__global__ __launch_bounds__(512, 2) void fused_pipe(
    const unsigned short* __restrict__ gf1,
    const unsigned short* __restrict__ whb,   // Whh bf16 [2][1024][256]
    const unsigned short* __restrict__ wb,    // Wih bf16 [2][1024][256]
    const float* __restrict__ bih, const float* __restrict__ bhh,
    const int* __restrict__ lengths,
    unsigned short* hb1, unsigned short* gf2, float* hout2,
    unsigned short* hx1, unsigned short* hx2, unsigned* sync)
{
  // sync: [0..15] scan1 wave flags, [16..31] scan2 wave flags, [32..33] gi2 credits
  const int bid = blockIdx.x;
  if (bid == 0)
    scan2cu<0>(gf1, whb, lengths, hb1, nullptr, hx1, sync, nullptr, 0);
  else if (bid == 8)
    scan2cu<0>(gf1, whb, lengths, hb1, nullptr, hx1, sync, nullptr, 1);
  else if (bid == 1)
    scan2cu<1>(gf2, whb + 262144, lengths, nullptr, hout2, hx2, sync + 16, sync + 32, 0);
  else if (bid == 9)
    scan2cu<1>(gf2, whb + 262144, lengths, nullptr, hout2, hx2, sync + 16, sync + 32, 1);
  else if (bid == 2)
    gi2b(0, hb1, wb + 262144, bih + 1024, bhh + 1024, gf2, sync, sync + 32);
  else if (bid == 10)
    gi2b(1, hb1, wb + 262144, bih + 1024, bhh + 1024, gf2, sync, sync + 33);
}

// ---------------- output projection: y = mask ? h2 @ W2^T + b2 : 0 ----------------
__global__ __launch_bounds__(256) void outproj(const float* __restrict__ h2,
                                               const float* __restrict__ W2,
                                               const float* __restrict__ b2,
                                               const int* __restrict__ lengths,
                                               float* __restrict__ y) {
  __shared__ float w2s[OUTF][HID + 1];
  __shared__ float hs[8][HID + 1];
  const int tid = threadIdx.x;
  const int r0 = blockIdx.x * 8;
  for (int i = tid; i < OUTF * HID; i += 256) w2s[i / HID][i % HID] = W2[i];
  for (int i = tid; i < 8 * HID; i += 256)
    hs[i / HID][i % HID] = h2[(size_t)(r0 + i / HID) * HID + (i % HID)];
  __syncthreads();
  for (int oi = tid; oi < 8 * OUTF; oi += 256) {
    const int r = oi / OUTF, o = oi % OUTF;
    const int row = r0 + r, t = row >> 4, b = row & 15;
    float acc = b2[o];
#pragma unroll 8
    for (int k = 0; k < HID; ++k) acc += hs[r][k] * w2s[o][k];
    y[(size_t)row * OUTF + o] = (t < lengths[b]) ? acc : 0.f;
  }
}

extern "C" void kernel_launch(void* const* d_in, const int* in_sizes, int n_in,
                              void* d_out, int out_size, void* d_ws, size_t ws_size,
                              hipStream_t stream) {
  const float* x      = (const float*)d_in[0];
  const int*   lengths= (const int*)d_in[1];
  const float* W1     = (const float*)d_in[2];
  const float* b1     = (const float*)d_in[3];
  const float* Wih    = (const float*)d_in[4];
  const float* Whh    = (const float*)d_in[5];
  const float* bih    = (const float*)d_in[6];
  const float* bhh    = (const float*)d_in[7];
  const float* W2     = (const float*)d_in[8];
  const float* b2     = (const float*)d_in[9];
  float* out = (float*)d_out;

  char* ws = (char*)d_ws;
  float*          h0   = (float*)(ws);                          // 32 MB
  unsigned short* gf1  = (unsigned short*)(ws + 33554432);      // 64 MB
  unsigned short* hb1  = (unsigned short*)(ws + 100663296);     // 16 MB
  unsigned short* gf2  = (unsigned short*)(ws + 117440512);     // 64 MB
  float*          h2o  = (float*)(ws + 184549376);              // 32 MB
  unsigned short* wb   = (unsigned short*)(ws + 218103808);     // 1 MB (Wih bf16)
  unsigned short* whb  = (unsigned short*)(ws + 219152384);     // 1 MB (Whh bf16)
  unsigned short* hx1  = (unsigned short*)(ws + 220200960);     // 32 KB exchange L1
  unsigned short* hx2  = (unsigned short*)(ws + 220233728);     // 32 KB exchange L2
  unsigned*       sync = (unsigned*)(ws + 220266496);           // flags/credits

  wpack<<<256, 256, 0, stream>>>(Wih, wb);
  wpack<<<256, 256, 0, stream>>>(Whh, whb);
  inproj<<<2048, 256, 0, stream>>>(x, W1, b1, h0);
  gi_mfma<<<2048, 256, 0, stream>>>(h0, wb, bih, bhh, gf1);

  // zero hx1+hx2+sync in one shot: h(0)=0 pre-published, flags/credits = 0
  hipMemsetAsync((void*)hx1, 0, 2 * 32768 + 1024, stream);
  fused_pipe<<<11, 512, 0, stream>>>(gf1, whb, wb, bih, bhh, lengths,
                                     hb1, gf2, h2o, hx1, hx2, sync);

  outproj<<<4096, 256, 0, stream>>>(h2o, W2, b2, lengths, out);
}

// Round 10
// 9318.235 us; speedup vs baseline: 2.5710x; 2.5710x over previous
//
#include <hip/hip_runtime.h>
#include <hip/hip_bf16.h>

#define T_STEPS 2048
#define HID 256
#define INF 72
#define OUTF 90
#define HSTR 528          // LDS h row stride for gi_mfma (bytes)

typedef __attribute__((ext_vector_type(4))) float f32x4;
typedef __attribute__((ext_vector_type(8))) short s16x8;
typedef unsigned long long u64;

__device__ __forceinline__ unsigned short f2bf(float f) {
  union { float f; unsigned u; } v; v.f = f;
  unsigned r = (v.u + 0x7FFFu + ((v.u >> 16) & 1u)) >> 16;   // RNE
  return (unsigned short)r;
}
__device__ __forceinline__ float bf2f(unsigned short s) {
  union { unsigned u; float f; } v; v.u = ((unsigned)s) << 16;
  return v.f;
}
__device__ __forceinline__ float sigm(float x) {
  return __builtin_amdgcn_rcpf(1.f + __builtin_amdgcn_exp2f(-1.44269504f * x));
}
__device__ __forceinline__ float tanh_f(float x) {
  return 1.f - 2.f * __builtin_amdgcn_rcpf(1.f + __builtin_amdgcn_exp2f(2.88539008f * x));
}

// ---- relaxed agent-scope (sc1) primitives — R8-proven, no fences ----
__device__ __forceinline__ u64 ld64(const u64* p) {
  return __hip_atomic_load(p, __ATOMIC_RELAXED, __HIP_MEMORY_SCOPE_AGENT);
}
__device__ __forceinline__ void st64(u64* p, u64 v) {
  __hip_atomic_store(p, v, __ATOMIC_RELAXED, __HIP_MEMORY_SCOPE_AGENT);
}
__device__ __forceinline__ void stflag(unsigned* p, unsigned v) {
  __hip_atomic_store(p, v, __ATOMIC_RELAXED, __HIP_MEMORY_SCOPE_AGENT);
}
__device__ __forceinline__ unsigned ldflag(const unsigned* p) {
  return __hip_atomic_load(p, __ATOMIC_RELAXED, __HIP_MEMORY_SCOPE_AGENT);
}
__device__ __forceinline__ void waitflag(const unsigned* p, unsigned target) {
  while (ldflag(p) < target) __builtin_amdgcn_s_sleep(1);
}
__device__ __forceinline__ unsigned wait2(const unsigned* creds, unsigned target, unsigned cred) {
  const u64* cp = (const u64*)creds;
  while (cred < target) {
    u64 v = ld64(cp);
    unsigned a = (unsigned)v, b = (unsigned)(v >> 32);
    cred = a < b ? a : b;
    if (cred < target) __builtin_amdgcn_s_sleep(2);
  }
  return cred;
}
__device__ __forceinline__ s16x8 ld16B_sc1(const unsigned short* p) {
  union { u64 u[2]; s16x8 v; } x;
  const u64* q = (const u64*)p;
  x.u[0] = ld64(q); x.u[1] = ld64(q + 1);
  return x.v;
}
// gi record: ROLE0 = pre-materialized gf1 (plain cached); ROLE1 = live gf2 (sc1)
template <int ROLE> __device__ __forceinline__ void ld_g(const unsigned short* p, s16x8& a, s16x8& b) {
  if constexpr (ROLE == 0) { a = *(const s16x8*)p; b = *(const s16x8*)(p + 8); }
  else {
    union { u64 u[2]; s16x8 v; } x, y;
    const u64* q = (const u64*)p;
    x.u[0] = ld64(q); x.u[1] = ld64(q + 1);
    y.u[0] = ld64(q + 2); y.u[1] = ld64(q + 3);
    a = x.v; b = y.v;
  }
}

// ---------------- input projection: h0 = relu(x @ W1^T + b1) ----------------
__global__ __launch_bounds__(256) void inproj(const float* __restrict__ x,
                                              const float* __restrict__ W1,
                                              const float* __restrict__ b1,
                                              float* __restrict__ h0) {
  __shared__ float w1s[HID][INF + 1];
  __shared__ float xs[16][INF];
  const int tid = threadIdx.x;
  const int r0 = blockIdx.x * 16;
  for (int i = tid; i < HID * INF; i += 256) w1s[i / INF][i % INF] = W1[i];
  for (int i = tid; i < 16 * INF; i += 256)
    xs[i / INF][i % INF] = x[(size_t)(r0 + i / INF) * INF + (i % INF)];
  __syncthreads();
  const float bj = b1[tid];
  for (int r = 0; r < 16; ++r) {
    float acc = bj;
#pragma unroll 8
    for (int k = 0; k < INF; ++k) acc += xs[r][k] * w1s[tid][k];
    h0[(size_t)(r0 + r) * HID + tid] = fmaxf(acc, 0.f);
  }
}

// ---------------- pack f32 -> bf16 ----------------
__global__ __launch_bounds__(256) void wpack(const float* __restrict__ w,
                                             unsigned short* __restrict__ o) {
  const size_t i = ((size_t)blockIdx.x * 256 + threadIdx.x) * 8;
  f32x4 a = *(const f32x4*)(w + i);
  f32x4 b = *(const f32x4*)(w + i + 4);
  s16x8 v;
#pragma unroll
  for (int e = 0; e < 4; ++e) { v[e] = (short)f2bf(a[e]); v[4 + e] = (short)f2bf(b[e]); }
  *(s16x8*)(o + i) = v;
}

// ------------- layer-1 gi GEMM (MFMA, swapped orientation): one block per t -------------
__global__ __launch_bounds__(256) void gi_mfma(const float* __restrict__ h,
                                               const unsigned short* __restrict__ wb,
                                               const float* __restrict__ bih,
                                               const float* __restrict__ bhh,
                                               unsigned short* __restrict__ gi) {
  __shared__ __align__(16) char hs[16 * HSTR];
  __shared__ float bs[1024];
  const int tid = threadIdx.x;
  const int t = blockIdx.x;
  const int lane = tid & 63;
  const int wg = tid >> 6;
  const int j = lane & 15;
  const int hi = lane >> 4;
  for (int i = tid; i < 1024; i += 256) bs[i] = bih[i] + bhh[i];
  {
    const int row = tid >> 4;
    const int c0 = (tid & 15) * 16;
    const float* src = h + ((size_t)t * 16 + row) * 256 + c0;
    f32x4 v0 = *(const f32x4*)(src);
    f32x4 v1 = *(const f32x4*)(src + 4);
    f32x4 v2 = *(const f32x4*)(src + 8);
    f32x4 v3 = *(const f32x4*)(src + 12);
    s16x8 p0, p1;
#pragma unroll
    for (int e = 0; e < 4; ++e) {
      p0[e] = (short)f2bf(v0[e]); p0[4 + e] = (short)f2bf(v1[e]);
      p1[e] = (short)f2bf(v2[e]); p1[4 + e] = (short)f2bf(v3[e]);
    }
    *(s16x8*)(hs + row * HSTR + c0 * 2) = p0;
    *(s16x8*)(hs + row * HSTR + c0 * 2 + 16) = p1;
  }
  __syncthreads();
  const int hread = j * HSTR + hi * 16;
  f32x4 acc[4][4] = {};   // [ug2][q]
#pragma unroll
  for (int kt = 0; kt < 8; ++kt) {
    const int k = kt * 32 + hi * 8;
    const s16x8 a = *(const s16x8*)(hs + hread + kt * 64);   // h[b=j][k] (B-frag)
#pragma unroll
    for (int ug2 = 0; ug2 < 4; ++ug2)
#pragma unroll
      for (int q = 0; q < 4; ++q) {
        const s16x8 bw = *(const s16x8*)(wb + (((size_t)(q << 8) + wg * 64 + ug2 * 16 + j) << 8) + k);
        acc[ug2][q] = __builtin_amdgcn_mfma_f32_16x16x32_bf16(bw, a, acc[ug2][q], 0, 0, 0);
      }
  }
#pragma unroll
  for (int ug2 = 0; ug2 < 4; ++ug2) {
    const int sw = wg * 4 + ug2;
    const int uT = sw * 16 + hi * 4;
    s16x8 o0, o1;
#pragma unroll
    for (int r = 0; r < 4; ++r) {
      o0[r]     = (short)f2bf(acc[ug2][0][r] + bs[uT + r]);
      o0[4 + r] = (short)f2bf(acc[ug2][1][r] + bs[256 + uT + r]);
      o1[r]     = (short)f2bf(acc[ug2][2][r] + bs[512 + uT + r]);
      o1[4 + r] = (short)f2bf(acc[ug2][3][r] + bs[768 + uT + r]);
    }
    unsigned short* dst = gi + ((size_t)(t * 16 + sw) * 64 + lane) * 16;
    *(s16x8*)(dst) = o0;
    *(s16x8*)(dst + 8) = o1;
  }
}

// ============ fused pipeline (6 blocks): scan1{0,1} | gi2{2,3} | scan2{4,5} ============
// Cross-CU: sc1 relaxed only (hx peer-half, hb1, gf2, flags/credits). Local: LDS + plain.

template <int ROLE>   // 0: layer1 (hb1 sc1 ys, posts hb1 credit); 1: layer2 (hout plain f32)
__device__ __forceinline__ void scan_tp(
    const unsigned short* __restrict__ gi,
    const unsigned short* __restrict__ whbL,  // Whh bf16 [1024][256]
    const int* __restrict__ lengths,
    unsigned short* __restrict__ hb1,
    float* __restrict__ hout,
    unsigned short* hx,                       // [4][16][256] bf16 exchange
    unsigned* myflag, unsigned* peerflag,
    unsigned* mycred,                         // ROLE0: hb1 group credit
    unsigned* creds,                          // ROLE1: gf2 credits (u64 pair)
    int half)
{
  __shared__ __align__(16) char hl[4 * 8192];   // own-half h, 4 slots, XOR-swizzled
  const int tid  = threadIdx.x;
  const int lane = tid & 63;
  const int w    = tid >> 6;
  const int j    = lane & 15;    // batch
  const int hi   = lane >> 4;
  const int uB   = half * 128 + w * 16;
  const int myu  = uB + hi * 4;

  s16x8 wfr[32];   // A-frags: W[unit uB+j][k] for 4 gates x 8 k-tiles (128 VGPRs)
#pragma unroll
  for (int kt = 0; kt < 8; ++kt)
#pragma unroll
    for (int q = 0; q < 4; ++q)
      wfr[kt * 4 + q] =
          *(const s16x8*)(whbL + ((size_t)(q * 256 + uB + j) << 8) + kt * 32 + hi * 8);

  const int len = lengths[j];
  float c[4] = {};
  unsigned short hprev[4] = {};

  // h(0)=0: own LDS slot 0 + own hx half slot 0, then flag=1
  const int lws = ((j << 9) + (myu << 1)) ^ ((j & 7) << 4);
  *(u64*)(hl + lws) = 0;
  st64((u64*)hx + ((j * 256 + myu) >> 2), 0);
  asm volatile("s_waitcnt vmcnt(0) lgkmcnt(0)" ::: "memory");
  __builtin_amdgcn_s_barrier();
  if (tid == 0) stflag(myflag, 1u);

  const unsigned short* gp = gi + ((size_t)(half * 8 + w) * 64 + lane) * 16;
  unsigned cred = 0;
  if (ROLE == 1) cred = wait2(creds, 8u, cred);   // BEFORE first gi touch (R5 discipline)
  s16x8 gE0, gE1, gO0, gO1;
  ld_g<ROLE>(gp, gE0, gE1);
  ld_g<ROLE>(gp + 16384, gO0, gO1);

  const int pbase = (1 - half) * 128;   // peer unit (k) range start

  for (int tg = 0; tg < T_STEPS; tg += 4) {
    if (ROLE == 1) {
      const unsigned target = (tg + 8 <= T_STEPS) ? (unsigned)(tg + 8) : (unsigned)T_STEPS;
      cred = wait2(creds, target, cred);
    }
#pragma unroll
    for (int ts = 0; ts < 4; ++ts) {
      const int t = tg + ts;
      s16x8& g0 = (ts & 1) ? gO0 : gE0;     // static even/odd register sets
      s16x8& g1 = (ts & 1) ? gO1 : gE1;
      const int cur = t & 3, nxt = (t + 1) & 3;

      waitflag(peerflag, (unsigned)(t + 1));   // peer published h(t) half

      s16x8 avp[4];                            // peer half via hx (sc1)
#pragma unroll
      for (int p = 0; p < 4; ++p) {
        const int k = pbase + p * 32 + hi * 8;
        avp[p] = ld16B_sc1(hx + cur * 4096 + j * 256 + k);
      }
      s16x8 avo[4];                            // own half via LDS
#pragma unroll
      for (int p = 0; p < 4; ++p) {
        const int k = half * 128 + p * 32 + hi * 8;
        const int off = cur * 8192 + (((j << 9) + (k << 1)) ^ ((j & 7) << 4));
        avo[p] = *(const s16x8*)(hl + off);
      }

      f32x4 acc[4];
#pragma unroll
      for (int r = 0; r < 4; ++r) {
        acc[0][r] = bf2f((unsigned short)g0[r]);
        acc[1][r] = bf2f((unsigned short)g0[4 + r]);
        acc[2][r] = bf2f((unsigned short)g1[r]);
        acc[3][r] = bf2f((unsigned short)g1[4 + r]);
      }
#pragma unroll
      for (int kt = 0; kt < 8; ++kt) {
        const s16x8 a = ((kt >> 2) == half) ? avo[kt & 3] : avp[kt & 3];
#pragma unroll
        for (int q = 0; q < 4; ++q)
          acc[q] = __builtin_amdgcn_mfma_f32_16x16x32_bf16(wfr[kt * 4 + q], a, acc[q], 0, 0, 0);
      }

      u64 hpk = 0, ypk = 0;
      f32x4 yv;
      const bool m = t < len;
#pragma unroll
      for (int r = 0; r < 4; ++r) {
        const float i_  = sigm(acc[0][r]);
        const float f_  = sigm(acc[1][r]);
        const float tg_ = tanh_f(acc[2][r]);
        const float o_  = sigm(acc[3][r]);
        const float cn = f_ * c[r] + i_ * tg_;
        const float hv = o_ * tanh_f(cn);
        c[r] = m ? cn : c[r];
        const unsigned short hb = m ? f2bf(hv) : hprev[r];
        hprev[r] = hb;
        hpk |= (u64)hb << (16 * r);
        if (ROLE == 0) ypk |= (u64)(m ? hb : (unsigned short)0) << (16 * r);
        else           yv[r] = m ? hv : 0.f;
      }
      // publish h(t+1): own LDS slot + peer-visible hx half; drain; one flag per CU
      *(u64*)(hl + nxt * 8192 + lws) = hpk;
      st64((u64*)hx + ((nxt * 4096 + j * 256 + myu) >> 2), hpk);
      asm volatile("s_waitcnt vmcnt(0) lgkmcnt(0)" ::: "memory");
      __builtin_amdgcn_s_barrier();
      if (tid == 0) stflag(myflag, (unsigned)(t + 2));
      // outputs AFTER the flag (off the per-step critical path; credit-gated below)
      if (ROLE == 0) st64((u64*)hb1 + (((size_t)t * 4096 + j * 256 + myu) >> 2), ypk);
      else           *(f32x4*)(hout + ((size_t)t * 16 + j) * 256 + myu) = yv;
      {  // gi prefetch t+2, stays in flight across the next step
        const int tn = (t + 2 < T_STEPS) ? t + 2 : T_STEPS - 1;
        ld_g<ROLE>(gp + (size_t)tn * 16384, g0, g1);
      }
    }
    if (ROLE == 0) {   // group credit for gi2: hb1[tg..tg+3] drained
      asm volatile("s_waitcnt vmcnt(0)" ::: "memory");
      __builtin_amdgcn_s_barrier();
      if (tid == 0) stflag(mycred, (unsigned)(tg + 4));
    }
  }
}

// ---- gi2 producer CU: 8 waves, one 16-unit tile each, Wih2 slice in 128 VGPRs ----
__device__ __forceinline__ void gi2b(int cu,
    const unsigned short* __restrict__ hb1,
    const unsigned short* __restrict__ wb2,
    const float* __restrict__ bih2, const float* __restrict__ bhh2,
    unsigned short* __restrict__ gf2,
    unsigned* creds_in, unsigned* mycred)
{
  const int tid = threadIdx.x;
  const int lane = tid & 63;
  const int w = tid >> 6;
  const int j = lane & 15;
  const int hi = lane >> 4;
  const int sw = cu * 8 + w;

  s16x8 wfr[32];
  float bsum[4][4];
#pragma unroll
  for (int kt = 0; kt < 8; ++kt)
#pragma unroll
    for (int q = 0; q < 4; ++q)
      wfr[kt * 4 + q] =
          *(const s16x8*)(wb2 + ((size_t)(q * 256 + sw * 16 + j) << 8) + kt * 32 + hi * 8);
#pragma unroll
  for (int q = 0; q < 4; ++q)
#pragma unroll
    for (int r = 0; r < 4; ++r) {
      const int col = q * 256 + sw * 16 + hi * 4 + r;
      bsum[q][r] = bih2[col] + bhh2[col];
    }

  unsigned cred = 0;
  for (int tg = 0; tg < T_STEPS; tg += 4) {
    cred = wait2(creds_in, (unsigned)(tg + 4), cred);
#pragma unroll
    for (int ts = 0; ts < 4; ++ts) {
      const int t = tg + ts;
      const unsigned short* ab = hb1 + (size_t)t * 4096 + j * 256 + hi * 8;
      s16x8 av[8];
#pragma unroll
      for (int kt = 0; kt < 8; ++kt) av[kt] = ld16B_sc1(ab + kt * 32);
      f32x4 acc[4];
#pragma unroll
      for (int q = 0; q < 4; ++q)
#pragma unroll
        for (int r = 0; r < 4; ++r) acc[q][r] = bsum[q][r];
#pragma unroll
      for (int kt = 0; kt < 8; ++kt)
#pragma unroll
        for (int q = 0; q < 4; ++q)
          acc[q] = __builtin_amdgcn_mfma_f32_16x16x32_bf16(wfr[kt * 4 + q], av[kt], acc[q], 0, 0, 0);
      u64 p0 = 0, q0 = 0, p1 = 0, q1 = 0;
#pragma unroll
      for (int r = 0; r < 4; ++r) {
        p0 |= (u64)f2bf(acc[0][r]) << (16 * r);
        q0 |= (u64)f2bf(acc[1][r]) << (16 * r);
        p1 |= (u64)f2bf(acc[2][r]) << (16 * r);
        q1 |= (u64)f2bf(acc[3][r]) << (16 * r);
      }
      u64* dst = (u64*)gf2 + ((size_t)(t * 16 + sw) * 64 + lane) * 4;
      st64(dst, p0); st64(dst + 1, q0); st64(dst + 2, p1); st64(dst + 3, q1);
    }
    asm volatile("s_waitcnt vmcnt(0)" ::: "memory");
    __builtin_amdgcn_s_barrier();
    if (tid == 0) stflag(mycred, (unsigned)(tg + 4));
  }
}

__global__ __launch_bounds__(512, 2) void fused_pipe(
    const unsigned short* __restrict__ gf1,
    const unsigned short* __restrict__ whb,   // Whh bf16 [2][1024][256]
    const unsigned short* __restrict__ wb,    // Wih bf16 [2][1024][256]
    const float* __restrict__ bih, const float* __restrict__ bhh,
    const int* __restrict__ lengths,
    unsigned short* hb1, unsigned short* gf2, float* hout2,
    unsigned short* hx1, unsigned short* hx2, unsigned* sync)
{
  // sync: [0,1]=scan1 CU flags, [2,3]=scan2 CU flags, [8,9]=hb1 creds, [12,13]=gf2 creds
  const int bid = blockIdx.x;
  if (bid == 0)
    scan_tp<0>(gf1, whb, lengths, hb1, nullptr, hx1, sync + 0, sync + 1, sync + 8, nullptr, 0);
  else if (bid == 1)
    scan_tp<0>(gf1, whb, lengths, hb1, nullptr, hx1, sync + 1, sync + 0, sync + 9, nullptr, 1);
  else if (bid == 2)
    gi2b(0, hb1, wb + 262144, bih + 1024, bhh + 1024, gf2, sync + 8, sync + 12);
  else if (bid == 3)
    gi2b(1, hb1, wb + 262144, bih + 1024, bhh + 1024, gf2, sync + 8, sync + 13);
  else if (bid == 4)
    scan_tp<1>(gf2, whb + 262144, lengths, nullptr, hout2, hx2, sync + 2, sync + 3, nullptr, sync + 12, 0);
  else
    scan_tp<1>(gf2, whb + 262144, lengths, nullptr, hout2, hx2, sync + 3, sync + 2, nullptr, sync + 12, 1);
}

// ---------------- output projection: y = mask ? h2 @ W2^T + b2 : 0 ----------------
__global__ __launch_bounds__(256) void outproj(const float* __restrict__ h2,
                                               const float* __restrict__ W2,
                                               const float* __restrict__ b2,
                                               const int* __restrict__ lengths,
                                               float* __restrict__ y) {
  __shared__ float w2s[OUTF][HID + 1];
  __shared__ float hs[8][HID + 1];
  const int tid = threadIdx.x;
  const int r0 = blockIdx.x * 8;
  for (int i = tid; i < OUTF * HID; i += 256) w2s[i / HID][i % HID] = W2[i];
  for (int i = tid; i < 8 * HID; i += 256)
    hs[i / HID][i % HID] = h2[(size_t)(r0 + i / HID) * HID + (i % HID)];
  __syncthreads();
  for (int oi = tid; oi < 8 * OUTF; oi += 256) {
    const int r = oi / OUTF, o = oi % OUTF;
    const int row = r0 + r, t = row >> 4, b = row & 15;
    float acc = b2[o];
#pragma unroll 8
    for (int k = 0; k < HID; ++k) acc += hs[r][k] * w2s[o][k];
    y[(size_t)row * OUTF + o] = (t < lengths[b]) ? acc : 0.f;
  }
}

extern "C" void kernel_launch(void* const* d_in, const int* in_sizes, int n_in,
                              void* d_out, int out_size, void* d_ws, size_t ws_size,
                              hipStream_t stream) {
  const float* x      = (const float*)d_in[0];
  const int*   lengths= (const int*)d_in[1];
  const float* W1     = (const float*)d_in[2];
  const float* b1     = (const float*)d_in[3];
  const float* Wih    = (const float*)d_in[4];
  const float* Whh    = (const float*)d_in[5];
  const float* bih    = (const float*)d_in[6];
  const float* bhh    = (const float*)d_in[7];
  const float* W2     = (const float*)d_in[8];
  const float* b2     = (const float*)d_in[9];
  float* out = (float*)d_out;

  char* ws = (char*)d_ws;
  float*          h0   = (float*)(ws);                          // 32 MB
  unsigned short* gf1  = (unsigned short*)(ws + 33554432);      // 64 MB
  unsigned short* hb1  = (unsigned short*)(ws + 100663296);     // 16 MB
  unsigned short* gf2  = (unsigned short*)(ws + 117440512);     // 64 MB
  float*          h2o  = (float*)(ws + 184549376);              // 32 MB
  unsigned short* wb   = (unsigned short*)(ws + 218103808);     // 1 MB (Wih bf16)
  unsigned short* whb  = (unsigned short*)(ws + 219152384);     // 1 MB (Whh bf16)
  unsigned short* hx1  = (unsigned short*)(ws + 220200960);     // 32 KB exchange L1
  unsigned short* hx2  = (unsigned short*)(ws + 220233728);     // 32 KB exchange L2
  unsigned*       sync = (unsigned*)(ws + 220266496);           // flags/credits

  wpack<<<256, 256, 0, stream>>>(Wih, wb);
  wpack<<<256, 256, 0, stream>>>(Whh, whb);
  inproj<<<2048, 256, 0, stream>>>(x, W1, b1, h0);
  gi_mfma<<<2048, 256, 0, stream>>>(h0, wb, bih, bhh, gf1);

  // zero hx1+hx2+sync each launch (h(0)=0 pre-published, flags/credits = 0)
  hipMemsetAsync((void*)hx1, 0, 2 * 32768 + 1024, stream);
  fused_pipe<<<6, 512, 0, stream>>>(gf1, whb, wb, bih, bhh, lengths,
                                    hb1, gf2, h2o, hx1, hx2, sync);

  outproj<<<4096, 256, 0, stream>>>(h2o, W2, b2, lengths, out);
}

// Round 11
// 9316.408 us; speedup vs baseline: 2.5715x; 1.0002x over previous
//
#include <hip/hip_runtime.h>
#include <hip/hip_bf16.h>

#define T_STEPS 2048
#define HID 256
#define INF 72
#define OUTF 90
#define HSTR 528          // LDS h row stride for gi_mfma (bytes)

typedef __attribute__((ext_vector_type(4))) float f32x4;
typedef __attribute__((ext_vector_type(8))) short s16x8;
typedef unsigned long long u64;

__device__ __forceinline__ unsigned short f2bf(float f) {
  union { float f; unsigned u; } v; v.f = f;
  unsigned r = (v.u + 0x7FFFu + ((v.u >> 16) & 1u)) >> 16;   // RNE
  return (unsigned short)r;
}
__device__ __forceinline__ float bf2f(unsigned short s) {
  union { unsigned u; float f; } v; v.u = ((unsigned)s) << 16;
  return v.f;
}
__device__ __forceinline__ float sigm(float x) {
  return __builtin_amdgcn_rcpf(1.f + __builtin_amdgcn_exp2f(-1.44269504f * x));
}
__device__ __forceinline__ float tanh_f(float x) {
  return 1.f - 2.f * __builtin_amdgcn_rcpf(1.f + __builtin_amdgcn_exp2f(2.88539008f * x));
}

// ---- relaxed agent-scope (sc1) primitives — R8-proven, no fences ----
__device__ __forceinline__ u64 ld64(const u64* p) {
  return __hip_atomic_load(p, __ATOMIC_RELAXED, __HIP_MEMORY_SCOPE_AGENT);
}
__device__ __forceinline__ void st64(u64* p, u64 v) {
  __hip_atomic_store(p, v, __ATOMIC_RELAXED, __HIP_MEMORY_SCOPE_AGENT);
}
__device__ __forceinline__ void stflag(unsigned* p, unsigned v) {
  __hip_atomic_store(p, v, __ATOMIC_RELAXED, __HIP_MEMORY_SCOPE_AGENT);
}
__device__ __forceinline__ unsigned ldflag(const unsigned* p) {
  return __hip_atomic_load(p, __ATOMIC_RELAXED, __HIP_MEMORY_SCOPE_AGENT);
}
__device__ __forceinline__ void waitflag(const unsigned* p, unsigned target) {
  while (ldflag(p) < target) __builtin_amdgcn_s_sleep(1);
}
__device__ __forceinline__ unsigned wait2(const unsigned* creds, unsigned target, unsigned cred) {
  const u64* cp = (const u64*)creds;
  while (cred < target) {
    u64 v = ld64(cp);
    unsigned a = (unsigned)v, b = (unsigned)(v >> 32);
    cred = a < b ? a : b;
    if (cred < target) __builtin_amdgcn_s_sleep(2);
  }
  return cred;
}
__device__ __forceinline__ s16x8 ld16B_sc1(const unsigned short* p) {
  union { u64 u[2]; s16x8 v; } x;
  const u64* q = (const u64*)p;
  x.u[0] = ld64(q); x.u[1] = ld64(q + 1);
  return x.v;
}
// gi record: ROLE0 = pre-materialized gf1 (plain cached); ROLE1 = live gf2 (sc1)
template <int ROLE> __device__ __forceinline__ void ld_g(const unsigned short* p, s16x8& a, s16x8& b) {
  if constexpr (ROLE == 0) { a = *(const s16x8*)p; b = *(const s16x8*)(p + 8); }
  else {
    union { u64 u[2]; s16x8 v; } x, y;
    const u64* q = (const u64*)p;
    x.u[0] = ld64(q); x.u[1] = ld64(q + 1);
    y.u[0] = ld64(q + 2); y.u[1] = ld64(q + 3);
    a = x.v; b = y.v;
  }
}

// ---------------- input projection: h0 = relu(x @ W1^T + b1) ----------------
__global__ __launch_bounds__(256) void inproj(const float* __restrict__ x,
                                              const float* __restrict__ W1,
                                              const float* __restrict__ b1,
                                              float* __restrict__ h0) {
  __shared__ float w1s[HID][INF + 1];
  __shared__ float xs[16][INF];
  const int tid = threadIdx.x;
  const int r0 = blockIdx.x * 16;
  for (int i = tid; i < HID * INF; i += 256) w1s[i / INF][i % INF] = W1[i];
  for (int i = tid; i < 16 * INF; i += 256)
    xs[i / INF][i % INF] = x[(size_t)(r0 + i / INF) * INF + (i % INF)];
  __syncthreads();
  const float bj = b1[tid];
  for (int r = 0; r < 16; ++r) {
    float acc = bj;
#pragma unroll 8
    for (int k = 0; k < INF; ++k) acc += xs[r][k] * w1s[tid][k];
    h0[(size_t)(r0 + r) * HID + tid] = fmaxf(acc, 0.f);
  }
}

// ---------------- pack f32 -> bf16 ----------------
__global__ __launch_bounds__(256) void wpack(const float* __restrict__ w,
                                             unsigned short* __restrict__ o) {
  const size_t i = ((size_t)blockIdx.x * 256 + threadIdx.x) * 8;
  f32x4 a = *(const f32x4*)(w + i);
  f32x4 b = *(const f32x4*)(w + i + 4);
  s16x8 v;
#pragma unroll
  for (int e = 0; e < 4; ++e) { v[e] = (short)f2bf(a[e]); v[4 + e] = (short)f2bf(b[e]); }
  *(s16x8*)(o + i) = v;
}

// ------------- layer-1 gi GEMM (MFMA, swapped orientation): one block per t -------------
__global__ __launch_bounds__(256) void gi_mfma(const float* __restrict__ h,
                                               const unsigned short* __restrict__ wb,
                                               const float* __restrict__ bih,
                                               const float* __restrict__ bhh,
                                               unsigned short* __restrict__ gi) {
  __shared__ __align__(16) char hs[16 * HSTR];
  __shared__ float bs[1024];
  const int tid = threadIdx.x;
  const int t = blockIdx.x;
  const int lane = tid & 63;
  const int wg = tid >> 6;
  const int j = lane & 15;
  const int hi = lane >> 4;
  for (int i = tid; i < 1024; i += 256) bs[i] = bih[i] + bhh[i];
  {
    const int row = tid >> 4;
    const int c0 = (tid & 15) * 16;
    const float* src = h + ((size_t)t * 16 + row) * 256 + c0;
    f32x4 v0 = *(const f32x4*)(src);
    f32x4 v1 = *(const f32x4*)(src + 4);
    f32x4 v2 = *(const f32x4*)(src + 8);
    f32x4 v3 = *(const f32x4*)(src + 12);
    s16x8 p0, p1;
#pragma unroll
    for (int e = 0; e < 4; ++e) {
      p0[e] = (short)f2bf(v0[e]); p0[4 + e] = (short)f2bf(v1[e]);
      p1[e] = (short)f2bf(v2[e]); p1[4 + e] = (short)f2bf(v3[e]);
    }
    *(s16x8*)(hs + row * HSTR + c0 * 2) = p0;
    *(s16x8*)(hs + row * HSTR + c0 * 2 + 16) = p1;
  }
  __syncthreads();
  const int hread = j * HSTR + hi * 16;
  f32x4 acc[4][4] = {};   // [ug2][q]
#pragma unroll
  for (int kt = 0; kt < 8; ++kt) {
    const int k = kt * 32 + hi * 8;
    const s16x8 a = *(const s16x8*)(hs + hread + kt * 64);   // h[b=j][k] (B-frag)
#pragma unroll
    for (int ug2 = 0; ug2 < 4; ++ug2)
#pragma unroll
      for (int q = 0; q < 4; ++q) {
        const s16x8 bw = *(const s16x8*)(wb + (((size_t)(q << 8) + wg * 64 + ug2 * 16 + j) << 8) + k);
        acc[ug2][q] = __builtin_amdgcn_mfma_f32_16x16x32_bf16(bw, a, acc[ug2][q], 0, 0, 0);
      }
  }
#pragma unroll
  for (int ug2 = 0; ug2 < 4; ++ug2) {
    const int sw = wg * 4 + ug2;
    const int uT = sw * 16 + hi * 4;
    s16x8 o0, o1;
#pragma unroll
    for (int r = 0; r < 4; ++r) {
      o0[r]     = (short)f2bf(acc[ug2][0][r] + bs[uT + r]);
      o0[4 + r] = (short)f2bf(acc[ug2][1][r] + bs[256 + uT + r]);
      o1[r]     = (short)f2bf(acc[ug2][2][r] + bs[512 + uT + r]);
      o1[4 + r] = (short)f2bf(acc[ug2][3][r] + bs[768 + uT + r]);
    }
    unsigned short* dst = gi + ((size_t)(t * 16 + sw) * 64 + lane) * 16;
    *(s16x8*)(dst) = o0;
    *(s16x8*)(dst + 8) = o1;
  }
}

// ============ fused pipeline (6 blocks): scan1{0,1} | gi2{2,3} | scan2{4,5} ============
// Cross-CU: sc1 relaxed only (hx peer-half, hb1, gf2, flags/credits). Local: LDS + plain.

template <int ROLE>   // 0: layer1 (hb1 sc1 ys, posts hb1 credit); 1: layer2 (hout plain f32)
__device__ __forceinline__ void scan_tp(
    const unsigned short* __restrict__ gi,
    const unsigned short* __restrict__ whbL,  // Whh bf16 [1024][256]
    const int* __restrict__ lengths,
    unsigned short* __restrict__ hb1,
    float* __restrict__ hout,
    unsigned short* hx,                       // [4][16][256] bf16 exchange
    unsigned* myflag, unsigned* peerflag,
    unsigned* mycred,                         // ROLE0: hb1 group credit
    unsigned* creds,                          // ROLE1: gf2 credits (u64 pair)
    int half)
{
  __shared__ __align__(16) char hl[4 * 8192];   // own-half h, 4 slots, XOR-swizzled
  const int tid  = threadIdx.x;
  const int lane = tid & 63;
  const int w    = tid >> 6;
  const int j    = lane & 15;    // batch
  const int hi   = lane >> 4;
  const int uB   = half * 128 + w * 16;
  const int myu  = uB + hi * 4;

  s16x8 wfr[32];   // A-frags: W[unit uB+j][k] for 4 gates x 8 k-tiles (128 VGPRs)
#pragma unroll
  for (int kt = 0; kt < 8; ++kt)
#pragma unroll
    for (int q = 0; q < 4; ++q)
      wfr[kt * 4 + q] =
          *(const s16x8*)(whbL + ((size_t)(q * 256 + uB + j) << 8) + kt * 32 + hi * 8);

  const int len = lengths[j];
  float c[4] = {};
  unsigned short hprev[4] = {};

  // h(0)=0: own LDS slot 0 + own hx half slot 0, then flag=1
  const int lws = ((j << 9) + (myu << 1)) ^ ((j & 7) << 4);
  *(u64*)(hl + lws) = 0;
  st64((u64*)hx + ((j * 256 + myu) >> 2), 0);
  asm volatile("s_waitcnt vmcnt(0) lgkmcnt(0)" ::: "memory");
  __builtin_amdgcn_s_barrier();
  if (tid == 0) stflag(myflag, 1u);

  const unsigned short* gp = gi + ((size_t)(half * 8 + w) * 64 + lane) * 16;
  unsigned cred = 0;
  if (ROLE == 1) cred = wait2(creds, 8u, cred);   // BEFORE first gi touch (R5 discipline)
  s16x8 gE0, gE1, gO0, gO1;
  ld_g<ROLE>(gp, gE0, gE1);
  ld_g<ROLE>(gp + 16384, gO0, gO1);

  const int pbase = (1 - half) * 128;   // peer unit (k) range start

  for (int tg = 0; tg < T_STEPS; tg += 4) {
    if (ROLE == 1) {
      const unsigned target = (tg + 8 <= T_STEPS) ? (unsigned)(tg + 8) : (unsigned)T_STEPS;
      cred = wait2(creds, target, cred);
    }
#pragma unroll
    for (int ts = 0; ts < 4; ++ts) {
      const int t = tg + ts;
      s16x8& g0 = (ts & 1) ? gO0 : gE0;     // static even/odd register sets
      s16x8& g1 = (ts & 1) ? gO1 : gE1;
      const int cur = t & 3, nxt = (t + 1) & 3;

      waitflag(peerflag, (unsigned)(t + 1));   // peer published h(t) half

      s16x8 avp[4];                            // peer half via hx (sc1)
#pragma unroll
      for (int p = 0; p < 4; ++p) {
        const int k = pbase + p * 32 + hi * 8;
        avp[p] = ld16B_sc1(hx + cur * 4096 + j * 256 + k);
      }
      s16x8 avo[4];                            // own half via LDS
#pragma unroll
      for (int p = 0; p < 4; ++p) {
        const int k = half * 128 + p * 32 + hi * 8;
        const int off = cur * 8192 + (((j << 9) + (k << 1)) ^ ((j & 7) << 4));
        avo[p] = *(const s16x8*)(hl + off);
      }

      f32x4 acc[4];
#pragma unroll
      for (int r = 0; r < 4; ++r) {
        acc[0][r] = bf2f((unsigned short)g0[r]);
        acc[1][r] = bf2f((unsigned short)g0[4 + r]);
        acc[2][r] = bf2f((unsigned short)g1[r]);
        acc[3][r] = bf2f((unsigned short)g1[4 + r]);
      }
#pragma unroll
      for (int kt = 0; kt < 8; ++kt) {
        const s16x8 a = ((kt >> 2) == half) ? avo[kt & 3] : avp[kt & 3];
#pragma unroll
        for (int q = 0; q < 4; ++q)
          acc[q] = __builtin_amdgcn_mfma_f32_16x16x32_bf16(wfr[kt * 4 + q], a, acc[q], 0, 0, 0);
      }

      u64 hpk = 0, ypk = 0;
      f32x4 yv;
      const bool m = t < len;
#pragma unroll
      for (int r = 0; r < 4; ++r) {
        const float i_  = sigm(acc[0][r]);
        const float f_  = sigm(acc[1][r]);
        const float tg_ = tanh_f(acc[2][r]);
        const float o_  = sigm(acc[3][r]);
        const float cn = f_ * c[r] + i_ * tg_;
        const float hv = o_ * tanh_f(cn);
        c[r] = m ? cn : c[r];
        const unsigned short hb = m ? f2bf(hv) : hprev[r];
        hprev[r] = hb;
        hpk |= (u64)hb << (16 * r);
        if (ROLE == 0) ypk |= (u64)(m ? hb : (unsigned short)0) << (16 * r);
        else           yv[r] = m ? hv : 0.f;
      }
      // publish h(t+1): own LDS slot + peer-visible hx half; drain; one flag per CU
      *(u64*)(hl + nxt * 8192 + lws) = hpk;
      st64((u64*)hx + ((nxt * 4096 + j * 256 + myu) >> 2), hpk);
      asm volatile("s_waitcnt vmcnt(0) lgkmcnt(0)" ::: "memory");
      __builtin_amdgcn_s_barrier();
      if (tid == 0) stflag(myflag, (unsigned)(t + 2));
      // outputs AFTER the flag (off the per-step critical path; credit-gated below)
      if (ROLE == 0) st64((u64*)hb1 + (((size_t)t * 4096 + j * 256 + myu) >> 2), ypk);
      else           *(f32x4*)(hout + ((size_t)t * 16 + j) * 256 + myu) = yv;
      {  // gi prefetch t+2, stays in flight across the next step
        const int tn = (t + 2 < T_STEPS) ? t + 2 : T_STEPS - 1;
        ld_g<ROLE>(gp + (size_t)tn * 16384, g0, g1);
      }
    }
    if (ROLE == 0) {   // group credit for gi2: hb1[tg..tg+3] drained
      asm volatile("s_waitcnt vmcnt(0)" ::: "memory");
      __builtin_amdgcn_s_barrier();
      if (tid == 0) stflag(mycred, (unsigned)(tg + 4));
    }
  }
}

// ---- gi2 producer CU: 8 waves, one 16-unit tile each, Wih2 slice in 128 VGPRs ----
__device__ __forceinline__ void gi2b(int cu,
    const unsigned short* __restrict__ hb1,
    const unsigned short* __restrict__ wb2,
    const float* __restrict__ bih2, const float* __restrict__ bhh2,
    unsigned short* __restrict__ gf2,
    unsigned* creds_in, unsigned* mycred)
{
  const int tid = threadIdx.x;
  const int lane = tid & 63;
  const int w = tid >> 6;
  const int j = lane & 15;
  const int hi = lane >> 4;
  const int sw = cu * 8 + w;

  s16x8 wfr[32];
  float bsum[4][4];
#pragma unroll
  for (int kt = 0; kt < 8; ++kt)
#pragma unroll
    for (int q = 0; q < 4; ++q)
      wfr[kt * 4 + q] =
          *(const s16x8*)(wb2 + ((size_t)(q * 256 + sw * 16 + j) << 8) + kt * 32 + hi * 8);
#pragma unroll
  for (int q = 0; q < 4; ++q)
#pragma unroll
    for (int r = 0; r < 4; ++r) {
      const int col = q * 256 + sw * 16 + hi * 4 + r;
      bsum[q][r] = bih2[col] + bhh2[col];
    }

  unsigned cred = 0;
  for (int tg = 0; tg < T_STEPS; tg += 4) {
    cred = wait2(creds_in, (unsigned)(tg + 4), cred);
#pragma unroll
    for (int ts = 0; ts < 4; ++ts) {
      const int t = tg + ts;
      const unsigned short* ab = hb1 + (size_t)t * 4096 + j * 256 + hi * 8;
      s16x8 av[8];
#pragma unroll
      for (int kt = 0; kt < 8; ++kt) av[kt] = ld16B_sc1(ab + kt * 32);
      f32x4 acc[4];
#pragma unroll
      for (int q = 0; q < 4; ++q)
#pragma unroll
        for (int r = 0; r < 4; ++r) acc[q][r] = bsum[q][r];
#pragma unroll
      for (int kt = 0; kt < 8; ++kt)
#pragma unroll
        for (int q = 0; q < 4; ++q)
          acc[q] = __builtin_amdgcn_mfma_f32_16x16x32_bf16(wfr[kt * 4 + q], av[kt], acc[q], 0, 0, 0);
      u64 p0 = 0, q0 = 0, p1 = 0, q1 = 0;
#pragma unroll
      for (int r = 0; r < 4; ++r) {
        p0 |= (u64)f2bf(acc[0][r]) << (16 * r);
        q0 |= (u64)f2bf(acc[1][r]) << (16 * r);
        p1 |= (u64)f2bf(acc[2][r]) << (16 * r);
        q1 |= (u64)f2bf(acc[3][r]) << (16 * r);
      }
      u64* dst = (u64*)gf2 + ((size_t)(t * 16 + sw) * 64 + lane) * 4;
      st64(dst, p0); st64(dst + 1, q0); st64(dst + 2, p1); st64(dst + 3, q1);
    }
    asm volatile("s_waitcnt vmcnt(0)" ::: "memory");
    __builtin_amdgcn_s_barrier();
    if (tid == 0) stflag(mycred, (unsigned)(tg + 4));
  }
}

__global__ __launch_bounds__(512, 2) void fused_pipe(
    const unsigned short* __restrict__ gf1,
    const unsigned short* __restrict__ whb,   // Whh bf16 [2][1024][256]
    const unsigned short* __restrict__ wb,    // Wih bf16 [2][1024][256]
    const float* __restrict__ bih, const float* __restrict__ bhh,
    const int* __restrict__ lengths,
    unsigned short* hb1, unsigned short* gf2, float* hout2,
    unsigned short* hx1, unsigned short* hx2, unsigned* sync)
{
  // sync: [0,1]=scan1 CU flags, [2,3]=scan2 CU flags, [8,9]=hb1 creds, [12,13]=gf2 creds
  const int bid = blockIdx.x;
  if (bid == 0)
    scan_tp<0>(gf1, whb, lengths, hb1, nullptr, hx1, sync + 0, sync + 1, sync + 8, nullptr, 0);
  else if (bid == 1)
    scan_tp<0>(gf1, whb, lengths, hb1, nullptr, hx1, sync + 1, sync + 0, sync + 9, nullptr, 1);
  else if (bid == 2)
    gi2b(0, hb1, wb + 262144, bih + 1024, bhh + 1024, gf2, sync + 8, sync + 12);
  else if (bid == 3)
    gi2b(1, hb1, wb + 262144, bih + 1024, bhh + 1024, gf2, sync + 8, sync + 13);
  else if (bid == 4)
    scan_tp<1>(gf2, whb + 262144, lengths, nullptr, hout2, hx2, sync + 2, sync + 3, nullptr, sync + 12, 0);
  else
    scan_tp<1>(gf2, whb + 262144, lengths, nullptr, hout2, hx2, sync + 3, sync + 2, nullptr, sync + 12, 1);
}

// ---------------- output projection: y = mask ? h2 @ W2^T + b2 : 0 ----------------
__global__ __launch_bounds__(256) void outproj(const float* __restrict__ h2,
                                               const float* __restrict__ W2,
                                               const float* __restrict__ b2,
                                               const int* __restrict__ lengths,
                                               float* __restrict__ y) {
  __shared__ float w2s[OUTF][HID + 1];
  __shared__ float hs[8][HID + 1];
  const int tid = threadIdx.x;
  const int r0 = blockIdx.x * 8;
  for (int i = tid; i < OUTF * HID; i += 256) w2s[i / HID][i % HID] = W2[i];
  for (int i = tid; i < 8 * HID; i += 256)
    hs[i / HID][i % HID] = h2[(size_t)(r0 + i / HID) * HID + (i % HID)];
  __syncthreads();
  for (int oi = tid; oi < 8 * OUTF; oi += 256) {
    const int r = oi / OUTF, o = oi % OUTF;
    const int row = r0 + r, t = row >> 4, b = row & 15;
    float acc = b2[o];
#pragma unroll 8
    for (int k = 0; k < HID; ++k) acc += hs[r][k] * w2s[o][k];
    y[(size_t)row * OUTF + o] = (t < lengths[b]) ? acc : 0.f;
  }
}

extern "C" void kernel_launch(void* const* d_in, const int* in_sizes, int n_in,
                              void* d_out, int out_size, void* d_ws, size_t ws_size,
                              hipStream_t stream) {
  const float* x      = (const float*)d_in[0];
  const int*   lengths= (const int*)d_in[1];
  const float* W1     = (const float*)d_in[2];
  const float* b1     = (const float*)d_in[3];
  const float* Wih    = (const float*)d_in[4];
  const float* Whh    = (const float*)d_in[5];
  const float* bih    = (const float*)d_in[6];
  const float* bhh    = (const float*)d_in[7];
  const float* W2     = (const float*)d_in[8];
  const float* b2     = (const float*)d_in[9];
  float* out = (float*)d_out;

  char* ws = (char*)d_ws;
  float*          h0   = (float*)(ws);                          // 32 MB
  unsigned short* gf1  = (unsigned short*)(ws + 33554432);      // 64 MB
  unsigned short* hb1  = (unsigned short*)(ws + 100663296);     // 16 MB
  unsigned short* gf2  = (unsigned short*)(ws + 117440512);     // 64 MB
  float*          h2o  = (float*)(ws + 184549376);              // 32 MB
  unsigned short* wb   = (unsigned short*)(ws + 218103808);     // 1 MB (Wih bf16)
  unsigned short* whb  = (unsigned short*)(ws + 219152384);     // 1 MB (Whh bf16)
  unsigned short* hx1  = (unsigned short*)(ws + 220200960);     // 32 KB exchange L1
  unsigned short* hx2  = (unsigned short*)(ws + 220233728);     // 32 KB exchange L2
  unsigned*       sync = (unsigned*)(ws + 220266496);           // flags/credits

  wpack<<<256, 256, 0, stream>>>(Wih, wb);
  wpack<<<256, 256, 0, stream>>>(Whh, whb);
  inproj<<<2048, 256, 0, stream>>>(x, W1, b1, h0);
  gi_mfma<<<2048, 256, 0, stream>>>(h0, wb, bih, bhh, gf1);

  // zero hx1+hx2+sync each launch (h(0)=0 pre-published, flags/credits = 0)
  hipMemsetAsync((void*)hx1, 0, 2 * 32768 + 1024, stream);
  fused_pipe<<<6, 512, 0, stream>>>(gf1, whb, wb, bih, bhh, lengths,
                                    hb1, gf2, h2o, hx1, hx2, sync);

  outproj<<<4096, 256, 0, stream>>>(h2o, W2, b2, lengths, out);
}